// Round 10
// baseline (227.109 us; speedup 1.0000x reference)
//
#include <hip/hip_runtime.h>
#include <math.h>

#define CCH 64
#define NLIST 64           // bin1 partitions
#define BIN_CHUNK 4096     // edges per bin chunk (256 thr * 16)
#define BIN_EPT 16
#define WROWS 128          // rows per window (fused LDS tile = 32 KB)
#define WSHIFT 7           // log2(WROWS)
#define NB2 64             // bin2 sublists per list (wpl <= NB2)
#define CAP2 1280          // pairs per window sublist (mean ~717, +20 sigma)
#define SPILL_CAP 131072

typedef float f4v __attribute__((ext_vector_type(4)));

__device__ __forceinline__ void nt_store_f4(float4 v, float4* p) {
    f4v x; x.x = v.x; x.y = v.y; x.z = v.z; x.w = v.w;
    __builtin_nontemporal_store(x, (f4v*)p);
}

__device__ __forceinline__ void atomicMaxF(float* addr, float v) {
    if (v >= 0.0f) atomicMax((int*)addr, __float_as_int(v));
    else           atomicMin((unsigned int*)addr, __float_as_uint(v));
}

// ---------------- last-resort fallback (round-1 atomic path) ----------------

__global__ __launch_bounds__(256) void fill_neginf_kernel(float4* out, int n4) {
    int i = blockIdx.x * blockDim.x + threadIdx.x;
    int stride = gridDim.x * blockDim.x;
    const float4 v = make_float4(-INFINITY, -INFINITY, -INFINITY, -INFINITY);
    for (; i < n4; i += stride) out[i] = v;
}

__global__ __launch_bounds__(256) void scatter_max_kernel(
        const float4* __restrict__ feat4, const int* __restrict__ src,
        const int* __restrict__ tgt, const int* __restrict__ ntypes,
        float* __restrict__ out, int E) {
    int gid = blockIdx.x * blockDim.x + threadIdx.x;
    int e = gid >> 4, q = gid & 15;
    if (e >= E) return;
    int n0 = ntypes[e*3+0], n1 = ntypes[e*3+1], n2 = ntypes[e*3+2];
    if ((n0 | n1 | n2) < 0) return;
    float4 f = feat4[(size_t)tgt[e] * 16 + q];
    float* o = out + (size_t)src[e] * CCH + q * 4;
    atomicMaxF(o+0, f.x); atomicMaxF(o+1, f.y);
    atomicMaxF(o+2, f.z); atomicMaxF(o+3, f.w);
}

__global__ __launch_bounds__(256) void finalize_kernel(
        float4* out, int n4, const int* feat_depth, float* scalar_slot) {
    int i = blockIdx.x * blockDim.x + threadIdx.x;
    int stride = gridDim.x * blockDim.x;
    for (; i < n4; i += stride) {
        float4 v = out[i];
        v.x = (v.x == -INFINITY) ? 0.0f : v.x;
        v.y = (v.y == -INFINITY) ? 0.0f : v.y;
        v.z = (v.z == -INFINITY) ? 0.0f : v.z;
        v.w = (v.w == -INFINITY) ? 0.0f : v.w;
        out[i] = v;
    }
    if (blockIdx.x == 0 && threadIdx.x == 0)
        scalar_slot[0] = (float)(feat_depth[0] + 1);
}

// ---------------- binned LDS-reduce path ----------------

__global__ __launch_bounds__(256) void zero4_kernel(int4* p, long long n4) {
    long long i = blockIdx.x * (long long)blockDim.x + threadIdx.x;
    long long stride = gridDim.x * (long long)blockDim.x;
    const int4 z = make_int4(0, 0, 0, 0);
    for (; i < n4; i += stride) p[i] = z;
}

// Phase 1: partition passing edges into NLIST row-range lists (coalesced runs).
__global__ __launch_bounds__(256) void bin_kernel(
        const int* __restrict__ src, const int* __restrict__ tgt,
        const int* __restrict__ ntypes,
        unsigned long long* __restrict__ lists, int listCap,
        int* __restrict__ gcur,
        unsigned long long* __restrict__ spill, int spillCap,
        int* __restrict__ spillCur,
        int shift, int E, int numChunks) {
    __shared__ unsigned long long pairs[BIN_CHUNK];
    __shared__ int hist[NLIST];
    __shared__ int lstart[NLIST];
    __shared__ int offs[NLIST];
    __shared__ int gbase[NLIST];
    __shared__ int sh_tot;

    for (int chunk = blockIdx.x; chunk < numChunks; chunk += gridDim.x) {
        long long e0 = (long long)chunk * BIN_CHUNK + (long long)threadIdx.x * BIN_EPT;

        if (threadIdx.x < NLIST) hist[threadIdx.x] = 0;
        __syncthreads();

        unsigned long long myPack[BIN_EPT];
        int myP[BIN_EPT];

        #pragma unroll
        for (int g = 0; g < BIN_EPT / 4; ++g) {
            long long eg = e0 + g * 4;
            int4 s4, t4, n0, n1, n2;
            if (eg + 4 <= E) {
                s4 = *(const int4*)(src + eg);
                t4 = *(const int4*)(tgt + eg);
                const int4* np = (const int4*)(ntypes + eg * 3);
                n0 = np[0]; n1 = np[1]; n2 = np[2];
            } else {
                s4 = make_int4(0,0,0,0); t4 = s4;
                n0 = make_int4(-1,-1,-1,-1); n1 = n0; n2 = n0;
                for (int k = 0; k < 4; ++k) {
                    long long e = eg + k;
                    if (e < E) {
                        (&s4.x)[k] = src[e]; (&t4.x)[k] = tgt[e];
                        int a = ntypes[e*3], b = ntypes[e*3+1], c = ntypes[e*3+2];
                        (&n0.x)[k] = a | b | c;
                        (&n1.x)[k] = 0; (&n2.x)[k] = 0;
                        continue;
                    }
                }
                int ntm[4] = {n0.x, n0.y, n0.z, n0.w};
                for (int k = 0; k < 4; ++k) {
                    int i = g*4 + k;
                    bool ok = (eg + k < E) && (ntm[k] >= 0);
                    int r = (&s4.x)[k];
                    myP[i] = ok ? (r >> shift) : -1;
                    myPack[i] = ((unsigned long long)(unsigned)r << 32) |
                                (unsigned)(&t4.x)[k];
                    if (ok) atomicAdd(&hist[myP[i]], 1);
                }
                continue;
            }
            int m0 = n0.x | n0.y | n0.z;
            int m1 = n0.w | n1.x | n1.y;
            int m2 = n1.z | n1.w | n2.x;
            int m3 = n2.y | n2.z | n2.w;
            int mm[4] = {m0, m1, m2, m3};
            int rr[4] = {s4.x, s4.y, s4.z, s4.w};
            int tt[4] = {t4.x, t4.y, t4.z, t4.w};
            #pragma unroll
            for (int k = 0; k < 4; ++k) {
                int i = g*4 + k;
                bool ok = mm[k] >= 0;
                myP[i] = ok ? (rr[k] >> shift) : -1;
                myPack[i] = ((unsigned long long)(unsigned)rr[k] << 32) |
                            (unsigned)tt[k];
                if (ok) atomicAdd(&hist[myP[i]], 1);
            }
        }
        __syncthreads();

        if (threadIdx.x < NLIST) {
            int h = hist[threadIdx.x];
            int incl = h;
            for (int o = 1; o < NLIST; o <<= 1) {
                int x = __shfl_up(incl, o, NLIST);
                if ((int)threadIdx.x >= o) incl += x;
            }
            lstart[threadIdx.x] = incl - h;
            offs[threadIdx.x]   = incl - h;
            if (threadIdx.x == NLIST - 1) sh_tot = incl;
            gbase[threadIdx.x] = atomicAdd(&gcur[threadIdx.x], h);
        }
        __syncthreads();

        #pragma unroll
        for (int i = 0; i < BIN_EPT; ++i) {
            int p = myP[i];
            if (p >= 0) {
                int pos = atomicAdd(&offs[p], 1);
                pairs[pos] = myPack[i];
            }
        }
        __syncthreads();

        int tot = sh_tot;
        for (int i = threadIdx.x; i < tot; i += 256) {
            unsigned long long pk = pairs[i];
            int p = (int)(pk >> 32) >> shift;
            int gpos = gbase[p] + (i - lstart[p]);
            if (gpos < listCap) {
                lists[(size_t)p * listCap + gpos] = pk;
            } else {
                int sp = atomicAdd(spillCur, 1);
                if (sp < spillCap) spill[sp] = pk;
            }
        }
        __syncthreads();
    }
}

// Phase 2: re-bin each list into per-window sublists (sequential read,
// LDS sort into <=NB2 bins, coalesced flush runs).
__global__ __launch_bounds__(256) void bin2_kernel(
        const unsigned long long* __restrict__ lists, int listCap,
        const int* __restrict__ gcur,
        unsigned long long* __restrict__ sub, int* __restrict__ cur2,
        unsigned long long* __restrict__ spill, int spillCap,
        int* __restrict__ spillCur, int wpl) {
    __shared__ unsigned long long pr[BIN_CHUNK];
    __shared__ int hist[NB2], lstart[NB2], offs[NB2], gbase[NB2];
    __shared__ int sh_tot;
    int l = blockIdx.x & (NLIST - 1);
    int s = blockIdx.x >> 6;                 // 16 chunk-parallel subs
    int cnt = gcur[l]; if (cnt > listCap) cnt = listCap;
    const unsigned long long* lst = lists + (size_t)l * listCap;
    int wmask = wpl - 1;

    for (int start = s * BIN_CHUNK; start < cnt; start += 16 * BIN_CHUNK) {
        int n = cnt - start; if (n > BIN_CHUNK) n = BIN_CHUNK;
        if (threadIdx.x < NB2) hist[threadIdx.x] = 0;
        __syncthreads();

        unsigned long long my[BIN_EPT]; int myw[BIN_EPT];
        #pragma unroll
        for (int k = 0; k < BIN_EPT; ++k) {
            int i = k * 256 + threadIdx.x;
            if (i < n) {
                unsigned long long pk = lst[start + i];
                int w = ((int)(pk >> 32) >> WSHIFT) & wmask;
                my[k] = pk; myw[k] = w;
                atomicAdd(&hist[w], 1);
            } else myw[k] = -1;
        }
        __syncthreads();

        if (threadIdx.x == 0) {
            int run = 0;
            for (int w = 0; w < wpl; ++w) {
                lstart[w] = run; offs[w] = run; run += hist[w];
            }
            sh_tot = run;
        }
        __syncthreads();
        if ((int)threadIdx.x < wpl)
            gbase[threadIdx.x] =
                atomicAdd(&cur2[l * wpl + threadIdx.x], hist[threadIdx.x]);
        __syncthreads();

        #pragma unroll
        for (int k = 0; k < BIN_EPT; ++k) {
            if (myw[k] >= 0) {
                int pos = atomicAdd(&offs[myw[k]], 1);
                pr[pos] = my[k];
            }
        }
        __syncthreads();

        int tot = sh_tot;
        for (int i = threadIdx.x; i < tot; i += 256) {
            unsigned long long pk = pr[i];
            int w = ((int)(pk >> 32) >> WSHIFT) & wmask;
            int gpos = gbase[w] + (i - lstart[w]);
            if (gpos < CAP2) {
                sub[((size_t)(l * wpl + w)) * CAP2 + gpos] = pk;
            } else {
                int sp = atomicAdd(spillCur, 1);
                if (sp < spillCap) spill[sp] = pk;
            }
        }
        __syncthreads();
    }
}

// Fused gather + LDS max-reduce + single coalesced write-out.
// One block per 128-row window; 32 KB LDS key tile.
// Inner loop is SOFTWARE-PIPELINED (register double-buffer, statically
// indexed): batch n+1's 8 feat loads are issued BEFORE batch n's ds_max
// cluster, so 8 loads stay in flight (counted vmcnt) while LDS atomics run.
// REPLAY-SAFETY: pairs loaded PER-LANE (vector path) into wave-private LDS
// slab, broadcast via uniform ds_read — never s_load through the stale K$.
__global__ __launch_bounds__(512, 8) void fused_kernel(
        const float* __restrict__ feat,
        const unsigned long long* __restrict__ sub,
        const int* __restrict__ cur2,
        float4* __restrict__ out4,
        const int* __restrict__ feat_depth, float* __restrict__ scalar_slot) {
    __shared__ unsigned int tile[WROWS * CCH];      // 32 KB
    __shared__ unsigned long long stage[8][64];     // 4 KB wave-private slabs
    int w = blockIdx.x;
    if (w == 0 && threadIdx.x == 0)
        scalar_slot[0] = (float)(feat_depth[0] + 1);

    for (int i = threadIdx.x; i < WROWS * CCH; i += 512) tile[i] = 0u;
    __syncthreads();

    int cnt = cur2[w]; if (cnt > CAP2) cnt = CAP2;
    const unsigned long long* sl = sub + (size_t)w * CAP2;
    int lane = threadIdx.x & 63;
    int wid = threadIdx.x >> 6;                  // 8 waves

    for (int i0 = wid * 64; i0 < cnt; i0 += 8 * 64) {
        int m = cnt - i0; if (m > 64) m = 64;
        // coalesced 512B per-lane pair load -> wave-private LDS slab
        if (lane < m) stage[wid][lane] = sl[i0 + lane];
        if (m == 64) {
            // pipelined full run: 8 batches of 8, loads one batch ahead
            unsigned long long pk[2][8];
            float f[2][8];
            #pragma unroll
            for (int u = 0; u < 8; ++u) pk[0][u] = stage[wid][u];
            #pragma unroll
            for (int u = 0; u < 8; ++u)
                f[0][u] = feat[(size_t)(unsigned)(pk[0][u] & 0xffffffffu) * CCH + lane];
            #pragma unroll
            for (int b = 0; b < 8; ++b) {
                const int cur = b & 1, nxt = cur ^ 1;   // compile-time (unrolled)
                if (b < 7) {
                    #pragma unroll
                    for (int u = 0; u < 8; ++u)
                        pk[nxt][u] = stage[wid][(b + 1) * 8 + u];
                    #pragma unroll
                    for (int u = 0; u < 8; ++u)
                        f[nxt][u] = feat[(size_t)(unsigned)(pk[nxt][u] & 0xffffffffu) * CCH + lane];
                }
                #pragma unroll
                for (int u = 0; u < 8; ++u) {
                    int rl = ((int)(pk[cur][u] >> 32)) & (WROWS - 1);
                    unsigned int bts = __float_as_uint(f[cur][u]);
                    unsigned int key = bts ^ ((unsigned int)((int)bts >> 31) | 0x80000000u);
                    atomicMax(&tile[rl * CCH + lane], key);  // ds_max, 2 ln/bank
                }
            }
        } else {
            for (int j = 0; j < m; ++j) {
                unsigned long long pk = stage[wid][j];
                int t = (int)(pk & 0xffffffffu);
                int rl = ((int)(pk >> 32)) & (WROWS - 1);
                unsigned int b = __float_as_uint(feat[(size_t)t * CCH + lane]);
                unsigned int key = b ^ ((unsigned int)((int)b >> 31) | 0x80000000u);
                atomicMax(&tile[rl * CCH + lane], key);
            }
        }
    }
    __syncthreads();

    const uint4* t4 = (const uint4*)tile;
    for (int i = threadIdx.x; i < WROWS * CCH / 4; i += 512) {
        uint4 k = t4[i];
        float4 v;
        v.x = (k.x == 0u) ? 0.0f
              : __uint_as_float((k.x & 0x80000000u) ? (k.x ^ 0x80000000u) : ~k.x);
        v.y = (k.y == 0u) ? 0.0f
              : __uint_as_float((k.y & 0x80000000u) ? (k.y ^ 0x80000000u) : ~k.y);
        v.z = (k.z == 0u) ? 0.0f
              : __uint_as_float((k.z & 0x80000000u) ? (k.z ^ 0x80000000u) : ~k.z);
        v.w = (k.w == 0u) ? 0.0f
              : __uint_as_float((k.w & 0x80000000u) ? (k.w ^ 0x80000000u) : ~k.w);
        nt_store_f4(v, out4 + (size_t)w * (WROWS * (CCH / 4)) + i);
    }
}

// Resolve spilled edges (rare): atomic max on top of fused output (only raises).
__global__ __launch_bounds__(256) void spill_kernel(
        const float4* __restrict__ feat4,
        const unsigned long long* __restrict__ spill,
        const int* __restrict__ spillCur, int spillCap,
        float* __restrict__ out) {
    int n = *spillCur; if (n > spillCap) n = spillCap;
    long long total = (long long)n * 16;
    long long stride = (long long)gridDim.x * blockDim.x;
    for (long long i = blockIdx.x * (long long)blockDim.x + threadIdx.x;
         i < total; i += stride) {
        int e = (int)(i >> 4), q = (int)(i & 15);
        unsigned long long pk = spill[e];
        int r = (int)(pk >> 32);
        int t = (int)(pk & 0xffffffffu);
        float4 f = feat4[(size_t)t * 16 + q];
        float* o = out + (size_t)r * CCH + q * 4;
        atomicMaxF(o+0, f.x); atomicMaxF(o+1, f.y);
        atomicMaxF(o+2, f.z); atomicMaxF(o+3, f.w);
    }
}

// If the spill list overflowed, rescan ALL edges with atomic max — idempotent.
__global__ __launch_bounds__(256) void repair_kernel(
        const float4* __restrict__ feat4, const int* __restrict__ src,
        const int* __restrict__ tgt, const int* __restrict__ ntypes,
        const int* __restrict__ spillCur, int spillCap,
        float* __restrict__ out, int E) {
    if (*spillCur <= spillCap) return;
    long long total = (long long)E * 16;
    long long stride = (long long)gridDim.x * blockDim.x;
    for (long long i = blockIdx.x * (long long)blockDim.x + threadIdx.x;
         i < total; i += stride) {
        int e = (int)(i >> 4), q = (int)(i & 15);
        if ((ntypes[e*3] | ntypes[e*3+1] | ntypes[e*3+2]) < 0) continue;
        float4 f = feat4[(size_t)tgt[e] * 16 + q];
        float* o = out + (size_t)src[e] * CCH + q * 4;
        atomicMaxF(o+0, f.x); atomicMaxF(o+1, f.y);
        atomicMaxF(o+2, f.z); atomicMaxF(o+3, f.w);
    }
}

extern "C" void kernel_launch(void* const* d_in, const int* in_sizes, int n_in,
                              void* d_out, int out_size, void* d_ws, size_t ws_size,
                              hipStream_t stream) {
    const float* feat       = (const float*)d_in[0];
    const int*   src_ids    = (const int*)d_in[1];
    const int*   tgt_ids    = (const int*)d_in[2];
    const int*   ntypes     = (const int*)d_in[3];
    const int*   feat_depth = (const int*)d_in[5];
    float* out = (float*)d_out;

    const int E = in_sizes[1];
    const int nout_elems = out_size - 1;
    const int N = nout_elems / CCH;      // output rows
    const int n4 = nout_elems / 4;

    // bin1 shift: rows-per-list = 2^shift1, <= 64 lists
    int shift1 = 0;
    while (((long long)(N - 1) >> shift1) > (NLIST - 1)) ++shift1;
    int wpl = (shift1 >= WSHIFT) ? (1 << (shift1 - WSHIFT)) : 0; // windows/list
    int windows = (wpl > 0) ? ((N + WROWS - 1) >> WSHIFT) : 0;

    // ws ints: gcur[64] | cur2[windows] | spillCur[16] | spill u64[SPILL_CAP]
    //          | lists1 u64[64*LC1] | sub u64[windows*CAP2]
    size_t wsInts = ws_size / sizeof(int);
    size_t zeroInts = (size_t)NLIST + windows + 16;
    int LC1 = 0;
    if (wpl >= 1 && wpl <= NB2 && windows > 0 && (N % WROWS) == 0 &&
        (zeroInts % 4) == 0) {
        for (int lc = 69632; lc >= 49152; lc -= 10240) {
            size_t need = zeroInts + 2ull * SPILL_CAP +
                          2ull * NLIST * lc + 2ull * windows * CAP2;
            if (need <= wsInts) { LC1 = lc; break; }
        }
    }

    if (LC1 == 0) {
        // last-resort: atomic scatter-max
        fill_neginf_kernel<<<2048, 256, 0, stream>>>((float4*)out, n4);
        long long total = (long long)E * 16;
        int blocks = (int)((total + 255) / 256);
        scatter_max_kernel<<<blocks, 256, 0, stream>>>(
            (const float4*)feat, src_ids, tgt_ids, ntypes, out, E);
        finalize_kernel<<<2048, 256, 0, stream>>>(
            (float4*)out, n4, feat_depth, out + nout_elems);
        return;
    }

    int* gcur     = (int*)d_ws;
    int* cur2     = gcur + NLIST;
    int* spillCur = cur2 + windows;
    unsigned long long* spill  = (unsigned long long*)(spillCur + 16);
    unsigned long long* lists1 = spill + SPILL_CAP;
    unsigned long long* sub    = lists1 + (size_t)NLIST * LC1;

    zero4_kernel<<<64, 256, 0, stream>>>((int4*)d_ws, (long long)(zeroInts / 4));

    int numChunks = (E + BIN_CHUNK - 1) / BIN_CHUNK;
    int binGrid = numChunks < 4096 ? numChunks : 4096;
    bin_kernel<<<binGrid, 256, 0, stream>>>(
        src_ids, tgt_ids, ntypes, lists1, LC1, gcur,
        spill, SPILL_CAP, spillCur, shift1, E, numChunks);

    bin2_kernel<<<NLIST * 16, 256, 0, stream>>>(
        lists1, LC1, gcur, sub, cur2, spill, SPILL_CAP, spillCur, wpl);

    fused_kernel<<<windows, 512, 0, stream>>>(
        feat, sub, cur2, (float4*)out, feat_depth, out + nout_elems);

    spill_kernel<<<2048, 256, 0, stream>>>(
        (const float4*)feat, spill, spillCur, SPILL_CAP, out);
    repair_kernel<<<4096, 256, 0, stream>>>(
        (const float4*)feat, src_ids, tgt_ids, ntypes,
        spillCur, SPILL_CAP, out, E);
}

// Round 11
// 203.562 us; speedup vs baseline: 1.1157x; 1.1157x over previous
//
#include <hip/hip_runtime.h>
#include <math.h>

#define CCH 64
#define NLIST 128          // bin1 partitions (7 bits)
#define BIN_CHUNK 4096     // edges per bin chunk (256 thr * 16)
#define BIN_EPT 16
#define WROWS 128          // rows per window (fused LDS tile = 32 KB)
#define WSHIFT 7           // log2(WROWS)
#define NB2 64             // bin2 sublists per list (wpl <= NB2)
#define CAP2 1280          // pairs per window sublist (mean ~717, +20 sigma)
#define SPILL_CAP 131072

typedef float f4v __attribute__((ext_vector_type(4)));

__device__ __forceinline__ void nt_store_f4(float4 v, float4* p) {
    f4v x; x.x = v.x; x.y = v.y; x.z = v.z; x.w = v.w;
    __builtin_nontemporal_store(x, (f4v*)p);
}

__device__ __forceinline__ void atomicMaxF(float* addr, float v) {
    if (v >= 0.0f) atomicMax((int*)addr, __float_as_int(v));
    else           atomicMin((unsigned int*)addr, __float_as_uint(v));
}

// ---------------- last-resort fallback (round-1 atomic path) ----------------

__global__ __launch_bounds__(256) void fill_neginf_kernel(float4* out, int n4) {
    int i = blockIdx.x * blockDim.x + threadIdx.x;
    int stride = gridDim.x * blockDim.x;
    const float4 v = make_float4(-INFINITY, -INFINITY, -INFINITY, -INFINITY);
    for (; i < n4; i += stride) out[i] = v;
}

__global__ __launch_bounds__(256) void scatter_max_kernel(
        const float4* __restrict__ feat4, const int* __restrict__ src,
        const int* __restrict__ tgt, const int* __restrict__ ntypes,
        float* __restrict__ out, int E) {
    int gid = blockIdx.x * blockDim.x + threadIdx.x;
    int e = gid >> 4, q = gid & 15;
    if (e >= E) return;
    int n0 = ntypes[e*3+0], n1 = ntypes[e*3+1], n2 = ntypes[e*3+2];
    if ((n0 | n1 | n2) < 0) return;
    float4 f = feat4[(size_t)tgt[e] * 16 + q];
    float* o = out + (size_t)src[e] * CCH + q * 4;
    atomicMaxF(o+0, f.x); atomicMaxF(o+1, f.y);
    atomicMaxF(o+2, f.z); atomicMaxF(o+3, f.w);
}

__global__ __launch_bounds__(256) void finalize_kernel(
        float4* out, int n4, const int* feat_depth, float* scalar_slot) {
    int i = blockIdx.x * blockDim.x + threadIdx.x;
    int stride = gridDim.x * blockDim.x;
    for (; i < n4; i += stride) {
        float4 v = out[i];
        v.x = (v.x == -INFINITY) ? 0.0f : v.x;
        v.y = (v.y == -INFINITY) ? 0.0f : v.y;
        v.z = (v.z == -INFINITY) ? 0.0f : v.z;
        v.w = (v.w == -INFINITY) ? 0.0f : v.w;
        out[i] = v;
    }
    if (blockIdx.x == 0 && threadIdx.x == 0)
        scalar_slot[0] = (float)(feat_depth[0] + 1);
}

// ---------------- binned LDS-reduce path (u32 packed pairs) ----------------
// pk32 = (rloc << TBITS) | t   where rloc = row & ((1<<shift1)-1), t = tgt.
// Requires TBITS + shift1 <= 32 (guarded at launch; else fallback).

__global__ __launch_bounds__(256) void zero4_kernel(int4* p, long long n4) {
    long long i = blockIdx.x * (long long)blockDim.x + threadIdx.x;
    long long stride = gridDim.x * (long long)blockDim.x;
    const int4 z = make_int4(0, 0, 0, 0);
    for (; i < n4; i += stride) p[i] = z;
}

// Phase 1: partition passing edges into NLIST row-range lists (coalesced runs).
// LDS keeps u64 (full row + tgt); global lists store packed u32.
__global__ __launch_bounds__(256) void bin_kernel(
        const int* __restrict__ src, const int* __restrict__ tgt,
        const int* __restrict__ ntypes,
        unsigned int* __restrict__ lists, int listCap,
        int* __restrict__ gcur,
        unsigned long long* __restrict__ spill, int spillCap,
        int* __restrict__ spillCur,
        int shift, int tbits, int E, int numChunks) {
    __shared__ unsigned long long pairs[BIN_CHUNK];
    __shared__ int hist[NLIST];
    __shared__ int lstart[NLIST];
    __shared__ int offs[NLIST];
    __shared__ int gbase[NLIST];
    __shared__ int sh_tot;
    const unsigned lmask = (1u << shift) - 1u;

    for (int chunk = blockIdx.x; chunk < numChunks; chunk += gridDim.x) {
        long long e0 = (long long)chunk * BIN_CHUNK + (long long)threadIdx.x * BIN_EPT;

        if (threadIdx.x < NLIST) hist[threadIdx.x] = 0;
        __syncthreads();

        unsigned long long myPack[BIN_EPT];
        int myP[BIN_EPT];

        #pragma unroll
        for (int g = 0; g < BIN_EPT / 4; ++g) {
            long long eg = e0 + g * 4;
            int4 s4, t4, n0, n1, n2;
            if (eg + 4 <= E) {
                s4 = *(const int4*)(src + eg);
                t4 = *(const int4*)(tgt + eg);
                const int4* np = (const int4*)(ntypes + eg * 3);
                n0 = np[0]; n1 = np[1]; n2 = np[2];
            } else {
                s4 = make_int4(0,0,0,0); t4 = s4;
                n0 = make_int4(-1,-1,-1,-1); n1 = n0; n2 = n0;
                for (int k = 0; k < 4; ++k) {
                    long long e = eg + k;
                    if (e < E) {
                        (&s4.x)[k] = src[e]; (&t4.x)[k] = tgt[e];
                        int a = ntypes[e*3], b = ntypes[e*3+1], c = ntypes[e*3+2];
                        (&n0.x)[k] = a | b | c;
                        (&n1.x)[k] = 0; (&n2.x)[k] = 0;
                        continue;
                    }
                }
                int ntm[4] = {n0.x, n0.y, n0.z, n0.w};
                for (int k = 0; k < 4; ++k) {
                    int i = g*4 + k;
                    bool ok = (eg + k < E) && (ntm[k] >= 0);
                    int r = (&s4.x)[k];
                    myP[i] = ok ? (r >> shift) : -1;
                    myPack[i] = ((unsigned long long)(unsigned)r << 32) |
                                (unsigned)(&t4.x)[k];
                    if (ok) atomicAdd(&hist[myP[i]], 1);
                }
                continue;
            }
            int m0 = n0.x | n0.y | n0.z;
            int m1 = n0.w | n1.x | n1.y;
            int m2 = n1.z | n1.w | n2.x;
            int m3 = n2.y | n2.z | n2.w;
            int mm[4] = {m0, m1, m2, m3};
            int rr[4] = {s4.x, s4.y, s4.z, s4.w};
            int tt[4] = {t4.x, t4.y, t4.z, t4.w};
            #pragma unroll
            for (int k = 0; k < 4; ++k) {
                int i = g*4 + k;
                bool ok = mm[k] >= 0;
                myP[i] = ok ? (rr[k] >> shift) : -1;
                myPack[i] = ((unsigned long long)(unsigned)rr[k] << 32) |
                            (unsigned)tt[k];
                if (ok) atomicAdd(&hist[myP[i]], 1);
            }
        }
        __syncthreads();

        if (threadIdx.x == 0) {
            int run = 0;
            for (int p = 0; p < NLIST; ++p) {
                lstart[p] = run; offs[p] = run; run += hist[p];
            }
            sh_tot = run;
        }
        __syncthreads();
        if (threadIdx.x < NLIST)
            gbase[threadIdx.x] = atomicAdd(&gcur[threadIdx.x], hist[threadIdx.x]);
        __syncthreads();

        #pragma unroll
        for (int i = 0; i < BIN_EPT; ++i) {
            int p = myP[i];
            if (p >= 0) {
                int pos = atomicAdd(&offs[p], 1);
                pairs[pos] = myPack[i];
            }
        }
        __syncthreads();

        int tot = sh_tot;
        for (int i = threadIdx.x; i < tot; i += 256) {
            unsigned long long pk = pairs[i];
            unsigned r = (unsigned)(pk >> 32);
            unsigned t = (unsigned)(pk & 0xffffffffu);
            int p = (int)(r >> shift);
            int gpos = gbase[p] + (i - lstart[p]);
            if (gpos < listCap) {
                lists[(size_t)p * listCap + gpos] = ((r & lmask) << tbits) | t;
            } else {
                int sp = atomicAdd(spillCur, 1);
                if (sp < spillCap) spill[sp] = pk;
            }
        }
        __syncthreads();
    }
}

// Phase 2: re-bin each list into per-window sublists (sequential u32 read,
// LDS sort into <=NB2 bins, coalesced flush runs).
__global__ __launch_bounds__(256) void bin2_kernel(
        const unsigned int* __restrict__ lists, int listCap,
        const int* __restrict__ gcur,
        unsigned int* __restrict__ sub, int* __restrict__ cur2,
        unsigned long long* __restrict__ spill, int spillCap,
        int* __restrict__ spillCur, int wpl, int shift, int tbits) {
    __shared__ unsigned int pr[BIN_CHUNK];
    __shared__ int hist[NB2], lstart[NB2], offs[NB2], gbase[NB2];
    __shared__ int sh_tot;
    int l = blockIdx.x & (NLIST - 1);
    int s = blockIdx.x / NLIST;              // 16 chunk-parallel subs
    int cnt = gcur[l]; if (cnt > listCap) cnt = listCap;
    const unsigned int* lst = lists + (size_t)l * listCap;
    int wmask = wpl - 1;
    int wsh = tbits + WSHIFT;
    unsigned tmask = (tbits >= 32) ? 0xffffffffu : ((1u << tbits) - 1u);

    for (int start = s * BIN_CHUNK; start < cnt; start += 16 * BIN_CHUNK) {
        int n = cnt - start; if (n > BIN_CHUNK) n = BIN_CHUNK;
        if (threadIdx.x < NB2) hist[threadIdx.x] = 0;
        __syncthreads();

        unsigned int my[BIN_EPT]; int myw[BIN_EPT];
        #pragma unroll
        for (int k = 0; k < BIN_EPT; ++k) {
            int i = k * 256 + threadIdx.x;
            if (i < n) {
                unsigned int pk = lst[start + i];
                int w = (int)(pk >> wsh) & wmask;
                my[k] = pk; myw[k] = w;
                atomicAdd(&hist[w], 1);
            } else myw[k] = -1;
        }
        __syncthreads();

        if (threadIdx.x == 0) {
            int run = 0;
            for (int w = 0; w < wpl; ++w) {
                lstart[w] = run; offs[w] = run; run += hist[w];
            }
            sh_tot = run;
        }
        __syncthreads();
        if ((int)threadIdx.x < wpl)
            gbase[threadIdx.x] =
                atomicAdd(&cur2[l * wpl + threadIdx.x], hist[threadIdx.x]);
        __syncthreads();

        #pragma unroll
        for (int k = 0; k < BIN_EPT; ++k) {
            if (myw[k] >= 0) {
                int pos = atomicAdd(&offs[myw[k]], 1);
                pr[pos] = my[k];
            }
        }
        __syncthreads();

        int tot = sh_tot;
        for (int i = threadIdx.x; i < tot; i += 256) {
            unsigned int pk = pr[i];
            int w = (int)(pk >> wsh) & wmask;
            int gpos = gbase[w] + (i - lstart[w]);
            if (gpos < CAP2) {
                sub[((size_t)(l * wpl + w)) * CAP2 + gpos] = pk;
            } else {
                int sp = atomicAdd(spillCur, 1);
                if (sp < spillCap) {
                    unsigned long long rfull =
                        ((unsigned long long)l << shift) | (pk >> tbits);
                    spill[sp] = (rfull << 32) | (pk & tmask);
                }
            }
        }
        __syncthreads();
    }
}

// Fused gather + LDS max-reduce + single coalesced write-out (round-9 form).
// One block per 128-row window; 32 KB LDS key tile; batches of 8 gathers.
// REPLAY-SAFETY: pairs loaded PER-LANE (vector path) into wave-private LDS
// slab, broadcast via uniform ds_read — never s_load through the stale K$.
__global__ __launch_bounds__(512, 8) void fused_kernel(
        const float* __restrict__ feat,
        const unsigned int* __restrict__ sub,
        const int* __restrict__ cur2,
        float4* __restrict__ out4, int tbits,
        const int* __restrict__ feat_depth, float* __restrict__ scalar_slot) {
    __shared__ unsigned int tile[WROWS * CCH];      // 32 KB
    __shared__ unsigned int stage[8][64];           // 2 KB wave-private slabs
    int w = blockIdx.x;
    if (w == 0 && threadIdx.x == 0)
        scalar_slot[0] = (float)(feat_depth[0] + 1);

    for (int i = threadIdx.x; i < WROWS * CCH; i += 512) tile[i] = 0u;
    __syncthreads();

    int cnt = cur2[w]; if (cnt > CAP2) cnt = CAP2;
    const unsigned int* sl = sub + (size_t)w * CAP2;
    int lane = threadIdx.x & 63;
    int wid = threadIdx.x >> 6;                  // 8 waves
    unsigned tmask = (tbits >= 32) ? 0xffffffffu : ((1u << tbits) - 1u);

    for (int i0 = wid * 64; i0 < cnt; i0 += 8 * 64) {
        int m = cnt - i0; if (m > 64) m = 64;
        // coalesced 256B per-lane pair load -> wave-private LDS slab
        if (lane < m) stage[wid][lane] = sl[i0 + lane];
        int j = 0;
        for (; j + 8 <= m; j += 8) {
            unsigned int pk[8];
            #pragma unroll
            for (int u = 0; u < 8; ++u) pk[u] = stage[wid][j + u]; // bcast read
            float f[8]; int rl[8];
            #pragma unroll
            for (int u = 0; u < 8; ++u) {
                unsigned t = pk[u] & tmask;
                rl[u] = (int)(pk[u] >> tbits) & (WROWS - 1);
                f[u] = feat[(size_t)t * CCH + lane];      // 256B coalesced
            }
            #pragma unroll
            for (int u = 0; u < 8; ++u) {
                unsigned int b = __float_as_uint(f[u]);
                unsigned int key = b ^ ((unsigned int)((int)b >> 31) | 0x80000000u);
                atomicMax(&tile[rl[u] * CCH + lane], key); // ds_max, 2 ln/bank
            }
        }
        for (; j < m; ++j) {
            unsigned int pk = stage[wid][j];
            unsigned t = pk & tmask;
            int rl = (int)(pk >> tbits) & (WROWS - 1);
            unsigned int b = __float_as_uint(feat[(size_t)t * CCH + lane]);
            unsigned int key = b ^ ((unsigned int)((int)b >> 31) | 0x80000000u);
            atomicMax(&tile[rl * CCH + lane], key);
        }
    }
    __syncthreads();

    const uint4* t4 = (const uint4*)tile;
    for (int i = threadIdx.x; i < WROWS * CCH / 4; i += 512) {
        uint4 k = t4[i];
        float4 v;
        v.x = (k.x == 0u) ? 0.0f
              : __uint_as_float((k.x & 0x80000000u) ? (k.x ^ 0x80000000u) : ~k.x);
        v.y = (k.y == 0u) ? 0.0f
              : __uint_as_float((k.y & 0x80000000u) ? (k.y ^ 0x80000000u) : ~k.y);
        v.z = (k.z == 0u) ? 0.0f
              : __uint_as_float((k.z & 0x80000000u) ? (k.z ^ 0x80000000u) : ~k.z);
        v.w = (k.w == 0u) ? 0.0f
              : __uint_as_float((k.w & 0x80000000u) ? (k.w ^ 0x80000000u) : ~k.w);
        nt_store_f4(v, out4 + (size_t)w * (WROWS * (CCH / 4)) + i);
    }
}

// Resolve spilled edges (rare): atomic max on top of fused output (only raises).
__global__ __launch_bounds__(256) void spill_kernel(
        const float4* __restrict__ feat4,
        const unsigned long long* __restrict__ spill,
        const int* __restrict__ spillCur, int spillCap,
        float* __restrict__ out) {
    int n = *spillCur; if (n > spillCap) n = spillCap;
    long long total = (long long)n * 16;
    long long stride = (long long)gridDim.x * blockDim.x;
    for (long long i = blockIdx.x * (long long)blockDim.x + threadIdx.x;
         i < total; i += stride) {
        int e = (int)(i >> 4), q = (int)(i & 15);
        unsigned long long pk = spill[e];
        int r = (int)(pk >> 32);
        int t = (int)(pk & 0xffffffffu);
        float4 f = feat4[(size_t)t * 16 + q];
        float* o = out + (size_t)r * CCH + q * 4;
        atomicMaxF(o+0, f.x); atomicMaxF(o+1, f.y);
        atomicMaxF(o+2, f.z); atomicMaxF(o+3, f.w);
    }
}

// If the spill list overflowed, rescan ALL edges with atomic max — idempotent.
__global__ __launch_bounds__(256) void repair_kernel(
        const float4* __restrict__ feat4, const int* __restrict__ src,
        const int* __restrict__ tgt, const int* __restrict__ ntypes,
        const int* __restrict__ spillCur, int spillCap,
        float* __restrict__ out, int E) {
    if (*spillCur <= spillCap) return;
    long long total = (long long)E * 16;
    long long stride = (long long)gridDim.x * blockDim.x;
    for (long long i = blockIdx.x * (long long)blockDim.x + threadIdx.x;
         i < total; i += stride) {
        int e = (int)(i >> 4), q = (int)(i & 15);
        if ((ntypes[e*3] | ntypes[e*3+1] | ntypes[e*3+2]) < 0) continue;
        float4 f = feat4[(size_t)tgt[e] * 16 + q];
        float* o = out + (size_t)src[e] * CCH + q * 4;
        atomicMaxF(o+0, f.x); atomicMaxF(o+1, f.y);
        atomicMaxF(o+2, f.z); atomicMaxF(o+3, f.w);
    }
}

extern "C" void kernel_launch(void* const* d_in, const int* in_sizes, int n_in,
                              void* d_out, int out_size, void* d_ws, size_t ws_size,
                              hipStream_t stream) {
    const float* feat       = (const float*)d_in[0];
    const int*   src_ids    = (const int*)d_in[1];
    const int*   tgt_ids    = (const int*)d_in[2];
    const int*   ntypes     = (const int*)d_in[3];
    const int*   feat_depth = (const int*)d_in[5];
    float* out = (float*)d_out;

    const int E    = in_sizes[1];
    const int N_IN = in_sizes[0] / CCH;  // feat rows
    const int nout_elems = out_size - 1;
    const int N = nout_elems / CCH;      // output rows
    const int n4 = nout_elems / 4;

    // bin1 shift: rows-per-list = 2^shift1, <= NLIST lists
    int shift1 = 0;
    while (((long long)(N - 1) >> shift1) > (NLIST - 1)) ++shift1;
    // tgt bits
    int tbits = 1;
    while (((long long)(N_IN - 1) >> tbits) != 0) ++tbits;
    int wpl = (shift1 >= WSHIFT) ? (1 << (shift1 - WSHIFT)) : 0; // windows/list
    int windows = (wpl > 0) ? ((N + WROWS - 1) >> WSHIFT) : 0;

    // ws ints: gcur[NLIST] | cur2[windows] | spillCur[16] | spill u64[SPILL_CAP]
    //          | lists1 u32[NLIST*LC1] | sub u32[windows*CAP2]
    size_t wsInts = ws_size / sizeof(int);
    size_t zeroInts = (size_t)NLIST + windows + 16;
    int LC1 = 0;
    if (wpl >= 1 && wpl <= NB2 && windows > 0 && (N % WROWS) == 0 &&
        (zeroInts % 4) == 0 && tbits + shift1 <= 32) {
        for (int lc = 32768; lc >= 24576; lc -= 4096) {
            size_t need = zeroInts + 2ull * SPILL_CAP +
                          (size_t)NLIST * lc + (size_t)windows * CAP2;
            if (need <= wsInts) { LC1 = lc; break; }
        }
    }

    if (LC1 == 0) {
        // last-resort: atomic scatter-max
        fill_neginf_kernel<<<2048, 256, 0, stream>>>((float4*)out, n4);
        long long total = (long long)E * 16;
        int blocks = (int)((total + 255) / 256);
        scatter_max_kernel<<<blocks, 256, 0, stream>>>(
            (const float4*)feat, src_ids, tgt_ids, ntypes, out, E);
        finalize_kernel<<<2048, 256, 0, stream>>>(
            (float4*)out, n4, feat_depth, out + nout_elems);
        return;
    }

    int* gcur     = (int*)d_ws;
    int* cur2     = gcur + NLIST;
    int* spillCur = cur2 + windows;
    unsigned long long* spill = (unsigned long long*)(spillCur + 16);
    unsigned int* lists1 = (unsigned int*)(spill + SPILL_CAP);
    unsigned int* sub    = lists1 + (size_t)NLIST * LC1;

    zero4_kernel<<<8, 256, 0, stream>>>((int4*)d_ws, (long long)(zeroInts / 4));

    int numChunks = (E + BIN_CHUNK - 1) / BIN_CHUNK;
    int binGrid = numChunks < 4096 ? numChunks : 4096;
    bin_kernel<<<binGrid, 256, 0, stream>>>(
        src_ids, tgt_ids, ntypes, lists1, LC1, gcur,
        spill, SPILL_CAP, spillCur, shift1, tbits, E, numChunks);

    bin2_kernel<<<NLIST * 16, 256, 0, stream>>>(
        lists1, LC1, gcur, sub, cur2, spill, SPILL_CAP, spillCur,
        wpl, shift1, tbits);

    fused_kernel<<<windows, 512, 0, stream>>>(
        feat, sub, cur2, (float4*)out, tbits, feat_depth, out + nout_elems);

    spill_kernel<<<2048, 256, 0, stream>>>(
        (const float4*)feat, spill, spillCur, SPILL_CAP, out);
    repair_kernel<<<4096, 256, 0, stream>>>(
        (const float4*)feat, src_ids, tgt_ids, ntypes,
        spillCur, SPILL_CAP, out, E);
}